// Round 7
// baseline (479.644 us; speedup 1.0000x reference)
//
#include <hip/hip_runtime.h>
#include <hip/hip_bf16.h>

// Problem constants (fixed by the reference)
#define D_DIM 256
#define H_HEADS 8
#define L_LVLS 4
#define P_PTS 4
#define DFF 2048
#define DH 32
#define NQ 900
#define B_BATCH 8
#define S_TOT 12240
#define NROW (NQ * B_BATCH)   // 7200
#define KPAD 928              // 900 keys padded to 29*32

typedef __attribute__((ext_vector_type(8))) short short8;
typedef __attribute__((ext_vector_type(4))) short short4v;
typedef __attribute__((ext_vector_type(4))) float f32x4;

// float -> bf16 round-to-nearest-even (inputs finite)
__device__ __forceinline__ short f2bf(float x) {
  union { float f; unsigned u; } v; v.f = x;
  unsigned r = v.u + 0x7fff + ((v.u >> 16) & 1);
  return (short)(r >> 16);
}
__device__ __forceinline__ float bf2f(unsigned short u) {
  union { unsigned u; float f; } v; v.u = ((unsigned)u) << 16; return v.f;
}

// ------------- fused preprocessing: weight conv (8 segs) + qk_bf/q_bf --------------
// blocks [0, NB_ADD): addconv on queries/qpe.  blocks [NB_ADD, ...): weight conv.
#define NB_ADD 1800
struct WConvArgs {
  const float* src[8];
  short* dst[8];
  int end[8];
  int total;
};
__global__ __launch_bounds__(256) void prep_kernel(
    WConvArgs a, const float* __restrict__ q, const float* __restrict__ p,
    short* __restrict__ qk_bf, short* __restrict__ q_bf) {
  if (blockIdx.x < NB_ADD) {
    int t = blockIdx.x * 256 + threadIdx.x;   // E/4 threads
    float4 x = ((const float4*)q)[t];
    float4 y = ((const float4*)p)[t];
    short4v s, ad;
    s.x = f2bf(x.x); s.y = f2bf(x.y); s.z = f2bf(x.z); s.w = f2bf(x.w);
    ad.x = f2bf(x.x + y.x); ad.y = f2bf(x.y + y.y);
    ad.z = f2bf(x.z + y.z); ad.w = f2bf(x.w + y.w);
    ((short4v*)q_bf)[t] = s;
    ((short4v*)qk_bf)[t] = ad;
  } else {
    int i = (blockIdx.x - NB_ADD) * 256 + threadIdx.x;
    if (i >= a.total) return;
    int seg = 0;
    while (seg < 7 && i >= a.end[seg]) seg++;
    int base = seg ? a.end[seg - 1] : 0;
    a.dst[seg][i - base] = f2bf(a.src[seg][i - base]);
  }
}

// ---------------- bf16 MFMA GEMM: C[M,N] = A[M,K] @ W[N,K]^T + bias ----------------
// Software-pipelined: next K-tile's global loads issue before the MFMAs, so the
// vmcnt wait (at the next LDS write) overlaps MFMA + ds_read of the current tile.
// TM = 128 (4 waves x 64x64) or 64 (4 waves x 32x64).  BN = 128.
// OMODE 0: fp32 flat (LDC).  1: bf16 flat (LDC).
// 2: QK head-split: m = nq*8+b, buf=n>>8 (0=q scaled by log2e/sqrt32, 1=k),
//    out[((buf*64 + b*8+h)*928 + nq)*32 + d].
// 3: V transposed: out[((b*8+h)*32 + d)*928 + nq].
template<bool RELU, int OMODE, int TM>
__global__ __launch_bounds__(256) void gemm_bf16(
    const short* __restrict__ A, const short* __restrict__ W,
    const float* __restrict__ bias, void* __restrict__ Cv,
    int M, int N, int K, int LDC) {
  constexpr int MI = (TM == 128) ? 4 : 2;
  __shared__ short As[TM * 40];
  __shared__ short Bs[128 * 40];
  int tid = threadIdx.x;
  int wave = tid >> 6, lane = tid & 63;
  int wm = wave >> 1, wn = wave & 1;
  int quad = lane >> 4, l16 = lane & 15;
  int m0 = blockIdx.y * TM, n0 = blockIdx.x * 128;
  int srowB = tid >> 1, shalfB = tid & 1;
  const short* bsrc = W + (long)(n0 + srowB) * K + shalfB * 16;
  short* bdst = &Bs[srowB * 40 + shalfB * 16];
  const short* asrc; short* adst; bool avalid;
  if (TM == 128) {
    int srow = tid >> 1, shalf = tid & 1;
    int am = m0 + srow;
    avalid = am < M;
    asrc = A + (long)(avalid ? am : 0) * K + shalf * 16;
    adst = &As[srow * 40 + shalf * 16];
  } else {
    int srow = tid >> 2, spart = tid & 3;
    int am = m0 + srow;
    avalid = am < M;
    asrc = A + (long)(avalid ? am : 0) * K + spart * 8;
    adst = &As[srow * 40 + spart * 8];
  }
  f32x4 acc[MI][4] = {};
  // preload tile 0
  short8 ta0 = {}, ta1 = {}, tb0, tb1;
  if (avalid) {
    ta0 = *(const short8*)(asrc);
    if (TM == 128) ta1 = *(const short8*)(asrc + 8);
  }
  tb0 = *(const short8*)(bsrc);
  tb1 = *(const short8*)(bsrc + 8);
  for (int k0 = 0; k0 < K; k0 += 32) {
    __syncthreads();
    *(short8*)adst = ta0;
    if (TM == 128) *(short8*)(adst + 8) = ta1;
    *(short8*)bdst = tb0;
    *(short8*)(bdst + 8) = tb1;
    __syncthreads();
    int kn = k0 + 32;
    if (kn < K) {
      if (avalid) {
        ta0 = *(const short8*)(asrc + kn);
        if (TM == 128) ta1 = *(const short8*)(asrc + kn + 8);
      }
      tb0 = *(const short8*)(bsrc + kn);
      tb1 = *(const short8*)(bsrc + kn + 8);
    }
    short8 af[MI], bf[4];
    #pragma unroll
    for (int i = 0; i < MI; i++)
      af[i] = *(const short8*)&As[(wm * (TM / 2) + i * 16 + l16) * 40 + quad * 8];
    #pragma unroll
    for (int j = 0; j < 4; j++)
      bf[j] = *(const short8*)&Bs[(wn * 64 + j * 16 + l16) * 40 + quad * 8];
    #pragma unroll
    for (int i = 0; i < MI; i++)
      #pragma unroll
      for (int j = 0; j < 4; j++)
        acc[i][j] = __builtin_amdgcn_mfma_f32_16x16x32_bf16(af[i], bf[j], acc[i][j], 0, 0, 0);
  }
  #pragma unroll
  for (int i = 0; i < MI; i++) {
    int mbase = m0 + wm * (TM / 2) + i * 16 + quad * 4;
    #pragma unroll
    for (int r = 0; r < 4; r++) {
      int m = mbase + r;
      if (m < M) {
        #pragma unroll
        for (int j = 0; j < 4; j++) {
          int n = n0 + wn * 64 + j * 16 + l16;
          float v = acc[i][j][r] + bias[n];
          if (RELU) v = fmaxf(v, 0.f);
          if (OMODE == 0) {
            ((float*)Cv)[(long)m * LDC + n] = v;
          } else if (OMODE == 1) {
            ((short*)Cv)[(long)m * LDC + n] = f2bf(v);
          } else if (OMODE == 2) {
            int nq = m >> 3, bb = m & 7;
            int buf = n >> 8, hh = (n >> 5) & 7, dd = n & 31;
            if (buf == 0) v *= 0.25503483f;   // log2(e)/sqrt(32)
            ((short*)Cv)[((long)(buf * 64 + bb * 8 + hh) * KPAD + nq) * 32 + dd] = f2bf(v);
          } else {
            int nq = m >> 3, bb = m & 7;
            int hh = n >> 5, dd = n & 31;
            ((short*)Cv)[((long)(bb * 8 + hh) * 32 + dd) * KPAD + nq] = f2bf(v);
          }
        }
      }
    }
  }
}

// ---------------- value GEMM v7: barrier-free, wave-independent ----------------
// Six prior variants (2-barrier x{TM128,TM64,BK64}, counted-vmcnt dbuf, burst
// staging, DRAM-sequential) all pinned at 64-72 us with total-TCC-traffic/time
// ~= 2.3 TB/s -- the shared structure was phase-locked waves (memory burst,
// barrier, memory-silent compute).  v7 removes phases entirely: NO LDS, NO
// barriers.  Each wave computes an independent 32x64 tile; A fragments are
// loaded per-lane direct from global fp32 (2 x float4 per fragment) and
// converted in-register; B fragments direct from global (L2-hot); 1-chunk
// prefetch.  16 independent staggered waves/CU keep memory issue continuous.
// A rows are re-read by the block's 4 waves -- extra reads hit L2, HBM traffic
// unchanged.  Chunk-ascending accumulation, identical MFMA operands/order and
// f2bf rounding -> bitwise-identical output.
__global__ __launch_bounds__(256) void gemm_val(
    const float* __restrict__ A, const short* __restrict__ W,
    const float* __restrict__ bias, short* __restrict__ C) {
  int tid = threadIdx.x;
  int wave = tid >> 6, lane = tid & 63;
  int quad = lane >> 4, l16 = lane & 15;
  int m0 = blockIdx.x * 32;
  // per-lane A row pointers (2 row fragments), A row for m=b*S+s is (s*B+b)
  const float* arow0;
  const float* arow1;
  {
    int m = m0 + l16;
    int b = m / S_TOT, s = m - b * S_TOT;
    arow0 = A + ((long)s * B_BATCH + b) * 256 + quad * 8;
    m = m0 + 16 + l16;
    b = m / S_TOT; s = m - b * S_TOT;
    arow1 = A + ((long)s * B_BATCH + b) * 256 + quad * 8;
  }
  const short* wb[4];
  #pragma unroll
  for (int j = 0; j < 4; j++)
    wb[j] = W + (long)(wave * 64 + j * 16 + l16) * 256 + quad * 8;

  f32x4 acc[2][4] = {};
  float4 a0l, a0h, a1l, a1h;       // current chunk A fp32
  float4 n0l, n0h, n1l, n1h;       // next chunk A fp32
  short8 bcur[4], bnxt[4];

  a0l = *(const float4*)(arow0);
  a0h = *(const float4*)(arow0 + 4);
  a1l = *(const float4*)(arow1);
  a1h = *(const float4*)(arow1 + 4);
  #pragma unroll
  for (int j = 0; j < 4; j++) bcur[j] = *(const short8*)(wb[j]);

  #pragma unroll
  for (int c = 0; c < 8; c++) {
    if (c < 7) {
      int off = (c + 1) * 32;
      n0l = *(const float4*)(arow0 + off);
      n0h = *(const float4*)(arow0 + off + 4);
      n1l = *(const float4*)(arow1 + off);
      n1h = *(const float4*)(arow1 + off + 4);
      #pragma unroll
      for (int j = 0; j < 4; j++) bnxt[j] = *(const short8*)(wb[j] + off);
    }
    short8 af0, af1;
    af0[0] = f2bf(a0l.x); af0[1] = f2bf(a0l.y); af0[2] = f2bf(a0l.z); af0[3] = f2bf(a0l.w);
    af0[4] = f2bf(a0h.x); af0[5] = f2bf(a0h.y); af0[6] = f2bf(a0h.z); af0[7] = f2bf(a0h.w);
    af1[0] = f2bf(a1l.x); af1[1] = f2bf(a1l.y); af1[2] = f2bf(a1l.z); af1[3] = f2bf(a1l.w);
    af1[4] = f2bf(a1h.x); af1[5] = f2bf(a1h.y); af1[6] = f2bf(a1h.z); af1[7] = f2bf(a1h.w);
    #pragma unroll
    for (int j = 0; j < 4; j++) {
      acc[0][j] = __builtin_amdgcn_mfma_f32_16x16x32_bf16(af0, bcur[j], acc[0][j], 0, 0, 0);
      acc[1][j] = __builtin_amdgcn_mfma_f32_16x16x32_bf16(af1, bcur[j], acc[1][j], 0, 0, 0);
    }
    a0l = n0l; a0h = n0h; a1l = n1l; a1h = n1h;
    #pragma unroll
    for (int j = 0; j < 4; j++) bcur[j] = bnxt[j];
  }

  #pragma unroll
  for (int i = 0; i < 2; i++) {
    int mbase = m0 + i * 16 + quad * 4;
    #pragma unroll
    for (int r = 0; r < 4; r++) {
      int m = mbase + r;
      #pragma unroll
      for (int j = 0; j < 4; j++) {
        int n = wave * 64 + j * 16 + l16;
        C[(long)m * 256 + n] = f2bf(acc[i][j][r] + bias[n]);
      }
    }
  }
}

// -------------------- MFMA flash self-attention --------------------
__global__ __launch_bounds__(256) void attn_mfma(
    const short* __restrict__ qk_h, const short* __restrict__ vT,
    short* __restrict__ att) {
  int bh = blockIdx.y; int b = bh >> 3, h = bh & 7;
  int tid = threadIdx.x; int wave = tid >> 6, lane = tid & 63;
  int quad = lane >> 4, l16 = lane & 15;
  int q0 = blockIdx.x * 128 + wave * 32;
  const short* qb = qk_h + (long)bh * KPAD * 32;
  const short* kb = qk_h + (long)(64 + bh) * KPAD * 32;
  const short* vb = vT + (long)bh * 32 * KPAD;
  __shared__ short P[4][32][40];
  short8 qfr[2];
  #pragma unroll
  for (int i = 0; i < 2; i++) {
    int qrow = q0 + i * 16 + l16; if (qrow > 927) qrow = 927;
    qfr[i] = *(const short8*)(qb + (long)qrow * 32 + quad * 8);
  }
  f32x4 acc[2][2] = {};
  float lsum[2] = {0.f, 0.f};
  const f32x4 zero = {0.f, 0.f, 0.f, 0.f};
  short8 ka = *(const short8*)(kb + (long)l16 * 32 + quad * 8);
  short8 kc = *(const short8*)(kb + (long)(16 + l16) * 32 + quad * 8);
  short8 va = *(const short8*)(vb + (long)l16 * KPAD + quad * 8);
  short8 vc = *(const short8*)(vb + (long)(16 + l16) * KPAD + quad * 8);
  for (int t = 0; t < 29; t++) {
    int k0 = t * 32;
    int kn = (t < 28) ? k0 + 32 : k0;
    short8 nka = *(const short8*)(kb + (long)(kn + l16) * 32 + quad * 8);
    short8 nkc = *(const short8*)(kb + (long)(kn + 16 + l16) * 32 + quad * 8);
    short8 nva = *(const short8*)(vb + (long)l16 * KPAD + kn + quad * 8);
    short8 nvc = *(const short8*)(vb + (long)(16 + l16) * KPAD + kn + quad * 8);
    f32x4 s[2][2];
    s[0][0] = __builtin_amdgcn_mfma_f32_16x16x32_bf16(ka, qfr[0], zero, 0, 0, 0);
    s[0][1] = __builtin_amdgcn_mfma_f32_16x16x32_bf16(ka, qfr[1], zero, 0, 0, 0);
    s[1][0] = __builtin_amdgcn_mfma_f32_16x16x32_bf16(kc, qfr[0], zero, 0, 0, 0);
    s[1][1] = __builtin_amdgcn_mfma_f32_16x16x32_bf16(kc, qfr[1], zero, 0, 0, 0);
    float p[2][2][4];
    #pragma unroll
    for (int kf = 0; kf < 2; kf++)
      #pragma unroll
      for (int qf = 0; qf < 2; qf++)
        #pragma unroll
        for (int r = 0; r < 4; r++) {
          float pe = __builtin_amdgcn_exp2f(s[kf][qf][r]);
          if (t == 28) {
            int kid = k0 + kf * 16 + quad * 4 + r;
            if (kid >= 900) pe = 0.f;
          }
          p[kf][qf][r] = pe;
          lsum[qf] += pe;
        }
    #pragma unroll
    for (int kf = 0; kf < 2; kf++)
      #pragma unroll
      for (int qf = 0; qf < 2; qf++)
        #pragma unroll
        for (int r = 0; r < 4; r += 2) {
          unsigned ua = __float_as_uint(p[kf][qf][r]) + 0x7fffu;
          unsigned ub = __float_as_uint(p[kf][qf][r + 1]) + 0x7fffu;
          unsigned pk = (ua >> 16) | (ub & 0xffff0000u);
          *(unsigned*)&P[wave][qf * 16 + l16][kf * 16 + quad * 4 + r] = pk;
        }
    #pragma unroll
    for (int qf = 0; qf < 2; qf++) {
      short8 pf = *(const short8*)&P[wave][qf * 16 + l16][quad * 8];
      acc[0][qf] = __builtin_amdgcn_mfma_f32_16x16x32_bf16(va, pf, acc[0][qf], 0, 0, 0);
      acc[1][qf] = __builtin_amdgcn_mfma_f32_16x16x32_bf16(vc, pf, acc[1][qf], 0, 0, 0);
    }
    ka = nka; kc = nkc; va = nva; vc = nvc;
  }
  #pragma unroll
  for (int qf = 0; qf < 2; qf++) {
    lsum[qf] += __shfl_xor(lsum[qf], 16);
    lsum[qf] += __shfl_xor(lsum[qf], 32);
  }
  #pragma unroll
  for (int df = 0; df < 2; df++)
    #pragma unroll
    for (int qf = 0; qf < 2; qf++) {
      int qg = q0 + qf * 16 + l16;
      if (qg < 900) {
        float inv = 1.f / lsum[qf];
        int d0 = df * 16 + quad * 4;
        short4v o4;
        o4.x = f2bf(acc[df][qf][0] * inv);
        o4.y = f2bf(acc[df][qf][1] * inv);
        o4.z = f2bf(acc[df][qf][2] * inv);
        o4.w = f2bf(acc[df][qf][3] * inv);
        *(short4v*)(att + (long)(qg * 8 + b) * 256 + h * 32 + d0) = o4;
      }
    }
}

// -------------------- residual + layernorm (optional bf16 / transposed bf16+pe out) ----
template<int BMODE>
__global__ __launch_bounds__(256) void resid_ln(
    const float* __restrict__ X, const float* __restrict__ R,
    const float* __restrict__ g, const float* __restrict__ be,
    float* __restrict__ out, short* __restrict__ obf,
    const float* __restrict__ qpe, short* __restrict__ obft) {
  int row = blockIdx.x;
  int d = threadIdx.x;
  long rrow;
  if (BMODE == 0) rrow = row;
  else { int b = row % B_BATCH; int n = row / B_BATCH; rrow = (long)b * NQ + n; }
  float x = X[(long)row * 256 + d] + R[rrow * 256 + d];
  float s1 = x, s2 = x * x;
  #pragma unroll
  for (int off = 32; off; off >>= 1) {
    s1 += __shfl_xor(s1, off);
    s2 += __shfl_xor(s2, off);
  }
  __shared__ float a1[4], a2[4];
  int w = d >> 6, lidx = d & 63;
  if (lidx == 0) { a1[w] = s1; a2[w] = s2; }
  __syncthreads();
  float S1 = a1[0] + a1[1] + a1[2] + a1[3];
  float S2 = a2[0] + a2[1] + a2[2] + a2[3];
  float mean = S1 * (1.f / 256.f);
  float var = S2 * (1.f / 256.f) - mean * mean;
  float y = (x - mean) * rsqrtf(var + 1e-5f) * g[d] + be[d];
  out[(long)row * 256 + d] = y;
  if (obf) obf[(long)row * 256 + d] = f2bf(y);
  if (obft) {   // row = n*B+b ; write bf16(y + qpe) at (b*NQ+n)
    int n = row >> 3, b = row & 7;
    obft[((long)b * NQ + n) * 256 + d] = f2bf(y + qpe[(long)row * 256 + d]);
  }
}

// -------------------- deformable-attention sampling (bf16 value, bf16 out) ------------
// offs/aw share a combined buffer with row stride 384.
__global__ __launch_bounds__(256) void deform_sample(
    const unsigned short* __restrict__ value, const float* __restrict__ offs,
    const float* __restrict__ aw, const float* __restrict__ qrp,
    short* __restrict__ samp) {
  int bq = blockIdx.x;  // b*NQ + q
  int b = bq / NQ, q = bq % NQ;
  int h = threadIdx.x >> 5, c = threadIdx.x & 31;
  __shared__ float Wl[8][16], Lx[8][16], Ly[8][16];
  if (c < 16) {
    float a = aw[(long)bq * 384 + h * 16 + c];
    float ox = offs[(long)bq * 384 + (h * 16 + c) * 2 + 0];
    float oy = offs[(long)bq * 384 + (h * 16 + c) * 2 + 1];
    const float* rp = qrp + ((long)q * B_BATCH + b) * 4;
    Lx[h][c] = rp[0] + ox * 0.25f * rp[2] * 0.5f;
    Ly[h][c] = rp[1] + oy * 0.25f * rp[3] * 0.5f;
    Wl[h][c] = a;
  }
  __syncthreads();
  if (threadIdx.x < 8) {
    int hh = threadIdx.x;
    float mx = -1e30f;
    for (int i = 0; i < 16; i++) mx = fmaxf(mx, Wl[hh][i]);
    float sm = 0.f;
    for (int i = 0; i < 16; i++) { float e = __expf(Wl[hh][i] - mx); Wl[hh][i] = e; sm += e; }
    float inv = 1.f / sm;
    for (int i = 0; i < 16; i++) Wl[hh][i] *= inv;
  }
  __syncthreads();
  const int lvlW[4] = {96, 48, 24, 12};
  const int lvlS[4] = {0, 9216, 11520, 12096};
  float acc = 0.f;
  const unsigned short* vb = value + (long)b * S_TOT * 256 + h * 32 + c;
  #pragma unroll
  for (int l = 0; l < 4; l++) {
    int ww = lvlW[l], hh2 = lvlW[l], st = lvlS[l];
    #pragma unroll
    for (int p = 0; p < 4; p++) {
      int lp = l * 4 + p;
      float wgt = Wl[h][lp];
      float x = Lx[h][lp] * ww - 0.5f;
      float y = Ly[h][lp] * hh2 - 0.5f;
      float x0f = floorf(x), y0f = floorf(y);
      float lx = x - x0f, ly = y - y0f;
      int x0 = (int)x0f, y0 = (int)y0f;
      #pragma unroll
      for (int cy = 0; cy < 2; cy++) {
        #pragma unroll
        for (int cx = 0; cx < 2; cx++) {
          int xi = x0 + cx, yi = y0 + cy;
          float cw = (cx ? lx : 1.f - lx) * (cy ? ly : 1.f - ly);
          bool valid = (xi >= 0) && (xi < ww) && (yi >= 0) && (yi < hh2);
          int xc = min(max(xi, 0), ww - 1);
          int yc = min(max(yi, 0), hh2 - 1);
          float vv = bf2f(vb[(long)(st + yc * ww + xc) * 256]);
          acc += (valid ? cw * wgt : 0.f) * vv;
        }
      }
    }
  }
  samp[(long)bq * 256 + h * 32 + c] = f2bf(acc);
}

// -------------------- host launch --------------------
extern "C" void kernel_launch(void* const* d_in, const int* in_sizes, int n_in,
                              void* d_out, int out_size, void* d_ws, size_t ws_size,
                              hipStream_t stream) {
  const float* queries = (const float*)d_in[0];
  const float* qpe     = (const float*)d_in[1];
  const float* qrp     = (const float*)d_in[2];
  const float* memory  = (const float*)d_in[3];
  const float* in_w    = (const float*)d_in[7];
  const float* in_b    = (const float*)d_in[8];
  const float* out_w   = (const float*)d_in[9];
  const float* out_b   = (const float*)d_in[10];
  const float* n1g = (const float*)d_in[11];
  const float* n1b = (const float*)d_in[12];
  const float* n2g = (const float*)d_in[13];
  const float* n2b = (const float*)d_in[14];
  const float* n3g = (const float*)d_in[15];
  const float* n3b = (const float*)d_in[16];
  const float* l1w = (const float*)d_in[17];
  const float* l1b = (const float*)d_in[18];
  const float* l2w = (const float*)d_in[19];
  const float* l2b = (const float*)d_in[20];
  const float* off_w = (const float*)d_in[21];
  const float* off_b = (const float*)d_in[22];
  const float* aw_w  = (const float*)d_in[23];
  const float* aw_b  = (const float*)d_in[24];
  const float* val_w = (const float*)d_in[25];
  const float* val_b = (const float*)d_in[26];
  const float* cout_w = (const float*)d_in[27];
  const float* cout_b = (const float*)d_in[28];

  float* ws = (float*)d_ws;
  const long E = (long)NROW * 256;        // 1,843,200
  float* slotA = ws + 0 * E;   // combined offs/aw [7200,384] (spans 2 slots)
  float* slotC = ws + 2 * E;   // sa -> ca -> ffn
  float* slotE = ws + 3 * E;   // q2
  float* slotF = ws + 4 * E;   // q3
  short* bfA = (short*)(ws + 5 * E);  // qk_bf -> samp_bf
  short* bfB = bfA + E;               // queries_bf -> qin_bf
  short* bfC = bfB + E;               // att_bf -> q3_bf
  short* wbf = bfC + E;               // weights bf16
  short* membt = wbf + 1540096;       // qk_h/vT -> hidden
  short* valbf = membt + 25067520;    // value bf16

  short* qk_h = membt;                          // [2][64][928][32]
  short* vT   = membt + 2L * 64 * KPAD * 32;    // [64][32][928]

  short* w_in   = wbf;                 // 196608 (Wq/Wk/Wv)
  short* w_out  = w_in + 196608;
  short* w_off  = w_out + 65536;       // [256,256]
  short* w_aw   = w_off + 65536;       // [128,256] (contiguous -> [384,256])
  short* w_val  = w_aw + 32768;
  short* w_cout = w_val + 65536;
  short* w_l1   = w_cout + 65536;
  short* w_l2   = w_l1 + 524288;
  float* bias_offaw = (float*)(valbf + 25067520);  // 384 floats

  dim3 blk(256);
  dim3 g7200(NROW);

  // 0. fused prep: weights -> bf16 + qk_bf/q_bf
  WConvArgs wa;
  wa.src[0] = in_w;  wa.dst[0] = w_in;
  wa.src[1] = out_w; wa.dst[1] = w_out;
  wa.src[2] = off_w; wa.dst[2] = w_off;
  wa.src[3] = aw_w;  wa.dst[3] = w_aw;
  wa.src[4] = val_w; wa.dst[4] = w_val;
  wa.src[5] = cout_w;wa.dst[5] = w_cout;
  wa.src[6] = l1w;   wa.dst[6] = w_l1;
  wa.src[7] = l2w;   wa.dst[7] = w_l2;
  int cs[8] = {196608, 65536, 65536, 32768, 65536, 65536, 524288, 524288};
  int acc0 = 0;
  for (int i = 0; i < 8; i++) { acc0 += cs[i]; wa.end[i] = acc0; }
  wa.total = acc0;
  int nbw = (acc0 + 255) / 256;
  prep_kernel<<<dim3(NB_ADD + nbw), blk, 0, stream>>>(wa, queries, qpe, bfA, bfB);
  hipMemcpyAsync(bias_offaw, off_b, 256 * sizeof(float), hipMemcpyDeviceToDevice, stream);
  hipMemcpyAsync(bias_offaw + 256, aw_b, 128 * sizeof(float), hipMemcpyDeviceToDevice, stream);

  // 1. in-proj: QK fused (N=512) -> head-split qk_h; V -> transposed vT
  gemm_bf16<false, 2, 128><<<dim3(4, 57), blk, 0, stream>>>(bfA, w_in, in_b, qk_h, NROW, 512, 256, 512);
  gemm_bf16<false, 3, 64><<<dim3(2, 113), blk, 0, stream>>>(bfB, w_in + 131072, in_b + 512, vT, NROW, 256, 256, 256);
  // 2. MFMA flash self-attention -> att_bf (bfC)
  attn_mfma<<<dim3(8, 64), blk, 0, stream>>>(qk_h, vT, bfC);
  // 3. out-proj -> sa (slotC)
  gemm_bf16<false, 0, 64><<<dim3(2, 113), blk, 0, stream>>>(bfC, w_out, out_b, slotC, NROW, 256, 256, 256);
  // 4. q2 = LN(queries + sa) [norm2] -> slotE; fused qin_bf -> bfB
  resid_ln<0><<<g7200, blk, 0, stream>>>(queries, slotC, n2g, n2b, slotE, nullptr, qpe, bfB);
  // 5. combined offsets+aw projection (N=384, LDC=384) -> slotA
  gemm_bf16<false, 0, 64><<<dim3(3, 113), blk, 0, stream>>>(bfB, w_off, bias_offaw, slotA, NROW, 384, 256, 384);
  // 6. value projection direct from fp32 memory -> valbf (barrier-free v7)
  gemm_val<<<dim3(3060), blk, 0, stream>>>(memory, w_val, val_b, valbf);
  // 7. deformable sampling -> samp_bf (bfA)
  deform_sample<<<g7200, blk, 0, stream>>>((const unsigned short*)valbf, slotA, slotA + 256, qrp, bfA);
  // 8. cross-attn output proj -> ca (slotC)
  gemm_bf16<false, 0, 64><<<dim3(2, 113), blk, 0, stream>>>(bfA, w_cout, cout_b, slotC, NROW, 256, 256, 256);
  // 9. q3 = LN(q2 + ca^T) [norm1] -> slotF (+ bf16 copy in bfC)
  resid_ln<1><<<g7200, blk, 0, stream>>>(slotE, slotC, n1g, n1b, slotF, bfC, nullptr, nullptr);
  // 10. FFN lin1 + relu -> hidden bf16 (membt reuse)
  gemm_bf16<true, 1, 128><<<dim3(16, 57), blk, 0, stream>>>(bfC, w_l1, l1b, membt, NROW, DFF, 256, DFF);
  // 11. FFN lin2 -> ffn (slotC)
  gemm_bf16<false, 0, 64><<<dim3(2, 113), blk, 0, stream>>>(membt, w_l2, l2b, slotC, NROW, 256, 2048, 256);
  // 12. out = LN(q3 + ffn) [norm3]
  resid_ln<0><<<g7200, blk, 0, stream>>>(slotF, slotC, n3g, n3b, (float*)d_out, nullptr, nullptr, nullptr);
}

// Round 8
// 426.462 us; speedup vs baseline: 1.1247x; 1.1247x over previous
//
#include <hip/hip_runtime.h>
#include <hip/hip_bf16.h>

// Problem constants (fixed by the reference)
#define D_DIM 256
#define H_HEADS 8
#define L_LVLS 4
#define P_PTS 4
#define DFF 2048
#define DH 32
#define NQ 900
#define B_BATCH 8
#define S_TOT 12240
#define NROW (NQ * B_BATCH)   // 7200
#define KPAD 928              // 900 keys padded to 29*32

typedef __attribute__((ext_vector_type(8))) short short8;
typedef __attribute__((ext_vector_type(4))) short short4v;
typedef __attribute__((ext_vector_type(4))) float f32x4;

// float -> bf16 round-to-nearest-even (inputs finite)
__device__ __forceinline__ short f2bf(float x) {
  union { float f; unsigned u; } v; v.f = x;
  unsigned r = v.u + 0x7fff + ((v.u >> 16) & 1);
  return (short)(r >> 16);
}
__device__ __forceinline__ float bf2f(unsigned short u) {
  union { unsigned u; float f; } v; v.u = ((unsigned)u) << 16; return v.f;
}

// ------------- fused preprocessing: weight conv (8 segs) + qk_bf/q_bf --------------
// blocks [0, NB_ADD): addconv on queries/qpe.  blocks [NB_ADD, ...): weight conv.
#define NB_ADD 1800
struct WConvArgs {
  const float* src[8];
  short* dst[8];
  int end[8];
  int total;
};
__global__ __launch_bounds__(256) void prep_kernel(
    WConvArgs a, const float* __restrict__ q, const float* __restrict__ p,
    short* __restrict__ qk_bf, short* __restrict__ q_bf) {
  if (blockIdx.x < NB_ADD) {
    int t = blockIdx.x * 256 + threadIdx.x;   // E/4 threads
    float4 x = ((const float4*)q)[t];
    float4 y = ((const float4*)p)[t];
    short4v s, ad;
    s.x = f2bf(x.x); s.y = f2bf(x.y); s.z = f2bf(x.z); s.w = f2bf(x.w);
    ad.x = f2bf(x.x + y.x); ad.y = f2bf(x.y + y.y);
    ad.z = f2bf(x.z + y.z); ad.w = f2bf(x.w + y.w);
    ((short4v*)q_bf)[t] = s;
    ((short4v*)qk_bf)[t] = ad;
  } else {
    int i = (blockIdx.x - NB_ADD) * 256 + threadIdx.x;
    if (i >= a.total) return;
    int seg = 0;
    while (seg < 7 && i >= a.end[seg]) seg++;
    int base = seg ? a.end[seg - 1] : 0;
    a.dst[seg][i - base] = f2bf(a.src[seg][i - base]);
  }
}

// ---------------- bf16 MFMA GEMM: C[M,N] = A[M,K] @ W[N,K]^T + bias ----------------
// Software-pipelined: next K-tile's global loads issue before the MFMAs, so the
// vmcnt wait (at the next LDS write) overlaps MFMA + ds_read of the current tile.
// TM = 128 (4 waves x 64x64) or 64 (4 waves x 32x64).  BN = 128.
// OMODE 0: fp32 flat (LDC).  1: bf16 flat (LDC).
// 2: QK head-split: m = nq*8+b, buf=n>>8 (0=q scaled by log2e/sqrt32, 1=k),
//    out[((buf*64 + b*8+h)*928 + nq)*32 + d].
// 3: V transposed: out[((b*8+h)*32 + d)*928 + nq].
template<bool RELU, int OMODE, int TM>
__global__ __launch_bounds__(256) void gemm_bf16(
    const short* __restrict__ A, const short* __restrict__ W,
    const float* __restrict__ bias, void* __restrict__ Cv,
    int M, int N, int K, int LDC) {
  constexpr int MI = (TM == 128) ? 4 : 2;
  __shared__ short As[TM * 40];
  __shared__ short Bs[128 * 40];
  int tid = threadIdx.x;
  int wave = tid >> 6, lane = tid & 63;
  int wm = wave >> 1, wn = wave & 1;
  int quad = lane >> 4, l16 = lane & 15;
  int m0 = blockIdx.y * TM, n0 = blockIdx.x * 128;
  int srowB = tid >> 1, shalfB = tid & 1;
  const short* bsrc = W + (long)(n0 + srowB) * K + shalfB * 16;
  short* bdst = &Bs[srowB * 40 + shalfB * 16];
  const short* asrc; short* adst; bool avalid;
  if (TM == 128) {
    int srow = tid >> 1, shalf = tid & 1;
    int am = m0 + srow;
    avalid = am < M;
    asrc = A + (long)(avalid ? am : 0) * K + shalf * 16;
    adst = &As[srow * 40 + shalf * 16];
  } else {
    int srow = tid >> 2, spart = tid & 3;
    int am = m0 + srow;
    avalid = am < M;
    asrc = A + (long)(avalid ? am : 0) * K + spart * 8;
    adst = &As[srow * 40 + spart * 8];
  }
  f32x4 acc[MI][4] = {};
  // preload tile 0
  short8 ta0 = {}, ta1 = {}, tb0, tb1;
  if (avalid) {
    ta0 = *(const short8*)(asrc);
    if (TM == 128) ta1 = *(const short8*)(asrc + 8);
  }
  tb0 = *(const short8*)(bsrc);
  tb1 = *(const short8*)(bsrc + 8);
  for (int k0 = 0; k0 < K; k0 += 32) {
    __syncthreads();
    *(short8*)adst = ta0;
    if (TM == 128) *(short8*)(adst + 8) = ta1;
    *(short8*)bdst = tb0;
    *(short8*)(bdst + 8) = tb1;
    __syncthreads();
    int kn = k0 + 32;
    if (kn < K) {
      if (avalid) {
        ta0 = *(const short8*)(asrc + kn);
        if (TM == 128) ta1 = *(const short8*)(asrc + kn + 8);
      }
      tb0 = *(const short8*)(bsrc + kn);
      tb1 = *(const short8*)(bsrc + kn + 8);
    }
    short8 af[MI], bf[4];
    #pragma unroll
    for (int i = 0; i < MI; i++)
      af[i] = *(const short8*)&As[(wm * (TM / 2) + i * 16 + l16) * 40 + quad * 8];
    #pragma unroll
    for (int j = 0; j < 4; j++)
      bf[j] = *(const short8*)&Bs[(wn * 64 + j * 16 + l16) * 40 + quad * 8];
    #pragma unroll
    for (int i = 0; i < MI; i++)
      #pragma unroll
      for (int j = 0; j < 4; j++)
        acc[i][j] = __builtin_amdgcn_mfma_f32_16x16x32_bf16(af[i], bf[j], acc[i][j], 0, 0, 0);
  }
  #pragma unroll
  for (int i = 0; i < MI; i++) {
    int mbase = m0 + wm * (TM / 2) + i * 16 + quad * 4;
    #pragma unroll
    for (int r = 0; r < 4; r++) {
      int m = mbase + r;
      if (m < M) {
        #pragma unroll
        for (int j = 0; j < 4; j++) {
          int n = n0 + wn * 64 + j * 16 + l16;
          float v = acc[i][j][r] + bias[n];
          if (RELU) v = fmaxf(v, 0.f);
          if (OMODE == 0) {
            ((float*)Cv)[(long)m * LDC + n] = v;
          } else if (OMODE == 1) {
            ((short*)Cv)[(long)m * LDC + n] = f2bf(v);
          } else if (OMODE == 2) {
            int nq = m >> 3, bb = m & 7;
            int buf = n >> 8, hh = (n >> 5) & 7, dd = n & 31;
            if (buf == 0) v *= 0.25503483f;   // log2(e)/sqrt(32)
            ((short*)Cv)[((long)(buf * 64 + bb * 8 + hh) * KPAD + nq) * 32 + dd] = f2bf(v);
          } else {
            int nq = m >> 3, bb = m & 7;
            int hh = n >> 5, dd = n & 31;
            ((short*)Cv)[((long)(bb * 8 + hh) * 32 + dd) * KPAD + nq] = f2bf(v);
          }
        }
      }
    }
  }
}

// ---------------- value GEMM v8: NO TRANSPOSE -- value stays in (s,b) layout ------
// Theory: every prior variant (v1-v7) read A rows at 8 KB stride because it
// computed output row m=b*S+s from input row s*B+b.  That stride is the one
// invariant shared by all seven; the ~2.3 TB/s cap tracked it, not occupancy /
// barriers / burst shape.  v8 keeps value in the INPUT's (s,b,d) layout: A is
// read fully linearly (consecutive rows contiguous), C written fully linearly.
// deform_sample's gather index changes to match (pure index arithmetic).
// Pipeline structure = v4 (2-barrier, BK=64, TM=64, proven best at 63 us).
// MFMA operands/order and f2bf rounding identical -> bitwise-identical output.
__global__ __launch_bounds__(256) void gemm_val(
    const float* __restrict__ A, const short* __restrict__ W,
    const float* __restrict__ bias, short* __restrict__ C) {
  __shared__ short As[2][64 * 40];
  __shared__ short Bs[2][128 * 40];
  int tid = threadIdx.x;
  int wave = tid >> 6, lane = tid & 63;
  int wm = wave >> 1, wn = wave & 1;
  int quad = lane >> 4, l16 = lane & 15;
  int m0 = blockIdx.y * 64, n0 = blockIdx.x * 128;
  // A staging: 4 threads/row, 16 consecutive floats each (K = spart*16 ..)
  int srow = tid >> 2, spart = tid & 3;
  int am = m0 + srow;
  const float* asrc = A + (long)am * 256 + spart * 16;   // LINEAR: row m contiguous
  short* adst = &As[spart >> 1][srow * 40 + (spart & 1) * 16];
  // B staging: 2 threads/row, 32 consecutive shorts each (K = shalfB*32 ..)
  int srowB = tid >> 1, shalfB = tid & 1;
  const short* bsrc = W + (long)(n0 + srowB) * 256 + shalfB * 32;
  short* bdst = &Bs[shalfB][srowB * 40];
  f32x4 acc[2][4] = {};
  // preload step 0
  float4 fa[4];
  short8 tb[4];
  #pragma unroll
  for (int u = 0; u < 4; u++) fa[u] = ((const float4*)asrc)[u];
  #pragma unroll
  for (int u = 0; u < 4; u++) tb[u] = ((const short8*)bsrc)[u];
  for (int k0 = 0; k0 < 256; k0 += 64) {
    __syncthreads();
    #pragma unroll
    for (int hh = 0; hh < 2; hh++) {
      float4 x = fa[2 * hh], y = fa[2 * hh + 1];
      short8 wa;
      wa[0] = f2bf(x.x); wa[1] = f2bf(x.y); wa[2] = f2bf(x.z); wa[3] = f2bf(x.w);
      wa[4] = f2bf(y.x); wa[5] = f2bf(y.y); wa[6] = f2bf(y.z); wa[7] = f2bf(y.w);
      *(short8*)(adst + hh * 8) = wa;
    }
    #pragma unroll
    for (int u = 0; u < 4; u++)
      *(short8*)(bdst + u * 8) = tb[u];
    __syncthreads();
    int kn = k0 + 64;
    if (kn < 256) {
      #pragma unroll
      for (int u = 0; u < 4; u++) fa[u] = ((const float4*)(asrc + kn))[u];
      #pragma unroll
      for (int u = 0; u < 4; u++) tb[u] = ((const short8*)(bsrc + kn))[u];
    }
    #pragma unroll
    for (int kk = 0; kk < 2; kk++) {
      short8 af[2], bf[4];
      #pragma unroll
      for (int i = 0; i < 2; i++)
        af[i] = *(const short8*)&As[kk][(wm * 32 + i * 16 + l16) * 40 + quad * 8];
      #pragma unroll
      for (int j = 0; j < 4; j++)
        bf[j] = *(const short8*)&Bs[kk][(wn * 64 + j * 16 + l16) * 40 + quad * 8];
      #pragma unroll
      for (int i = 0; i < 2; i++)
        #pragma unroll
        for (int j = 0; j < 4; j++)
          acc[i][j] = __builtin_amdgcn_mfma_f32_16x16x32_bf16(af[i], bf[j], acc[i][j], 0, 0, 0);
    }
  }
  #pragma unroll
  for (int i = 0; i < 2; i++) {
    int mbase = m0 + wm * 32 + i * 16 + quad * 4;
    #pragma unroll
    for (int r = 0; r < 4; r++) {
      int m = mbase + r;
      #pragma unroll
      for (int j = 0; j < 4; j++) {
        int n = n0 + wn * 64 + j * 16 + l16;
        C[(long)m * 256 + n] = f2bf(acc[i][j][r] + bias[n]);  // LINEAR write
      }
    }
  }
}

// -------------------- MFMA flash self-attention --------------------
__global__ __launch_bounds__(256) void attn_mfma(
    const short* __restrict__ qk_h, const short* __restrict__ vT,
    short* __restrict__ att) {
  int bh = blockIdx.y; int b = bh >> 3, h = bh & 7;
  int tid = threadIdx.x; int wave = tid >> 6, lane = tid & 63;
  int quad = lane >> 4, l16 = lane & 15;
  int q0 = blockIdx.x * 128 + wave * 32;
  const short* qb = qk_h + (long)bh * KPAD * 32;
  const short* kb = qk_h + (long)(64 + bh) * KPAD * 32;
  const short* vb = vT + (long)bh * 32 * KPAD;
  __shared__ short P[4][32][40];
  short8 qfr[2];
  #pragma unroll
  for (int i = 0; i < 2; i++) {
    int qrow = q0 + i * 16 + l16; if (qrow > 927) qrow = 927;
    qfr[i] = *(const short8*)(qb + (long)qrow * 32 + quad * 8);
  }
  f32x4 acc[2][2] = {};
  float lsum[2] = {0.f, 0.f};
  const f32x4 zero = {0.f, 0.f, 0.f, 0.f};
  short8 ka = *(const short8*)(kb + (long)l16 * 32 + quad * 8);
  short8 kc = *(const short8*)(kb + (long)(16 + l16) * 32 + quad * 8);
  short8 va = *(const short8*)(vb + (long)l16 * KPAD + quad * 8);
  short8 vc = *(const short8*)(vb + (long)(16 + l16) * KPAD + quad * 8);
  for (int t = 0; t < 29; t++) {
    int k0 = t * 32;
    int kn = (t < 28) ? k0 + 32 : k0;
    short8 nka = *(const short8*)(kb + (long)(kn + l16) * 32 + quad * 8);
    short8 nkc = *(const short8*)(kb + (long)(kn + 16 + l16) * 32 + quad * 8);
    short8 nva = *(const short8*)(vb + (long)l16 * KPAD + kn + quad * 8);
    short8 nvc = *(const short8*)(vb + (long)(16 + l16) * KPAD + kn + quad * 8);
    f32x4 s[2][2];
    s[0][0] = __builtin_amdgcn_mfma_f32_16x16x32_bf16(ka, qfr[0], zero, 0, 0, 0);
    s[0][1] = __builtin_amdgcn_mfma_f32_16x16x32_bf16(ka, qfr[1], zero, 0, 0, 0);
    s[1][0] = __builtin_amdgcn_mfma_f32_16x16x32_bf16(kc, qfr[0], zero, 0, 0, 0);
    s[1][1] = __builtin_amdgcn_mfma_f32_16x16x32_bf16(kc, qfr[1], zero, 0, 0, 0);
    float p[2][2][4];
    #pragma unroll
    for (int kf = 0; kf < 2; kf++)
      #pragma unroll
      for (int qf = 0; qf < 2; qf++)
        #pragma unroll
        for (int r = 0; r < 4; r++) {
          float pe = __builtin_amdgcn_exp2f(s[kf][qf][r]);
          if (t == 28) {
            int kid = k0 + kf * 16 + quad * 4 + r;
            if (kid >= 900) pe = 0.f;
          }
          p[kf][qf][r] = pe;
          lsum[qf] += pe;
        }
    #pragma unroll
    for (int kf = 0; kf < 2; kf++)
      #pragma unroll
      for (int qf = 0; qf < 2; qf++)
        #pragma unroll
        for (int r = 0; r < 4; r += 2) {
          unsigned ua = __float_as_uint(p[kf][qf][r]) + 0x7fffu;
          unsigned ub = __float_as_uint(p[kf][qf][r + 1]) + 0x7fffu;
          unsigned pk = (ua >> 16) | (ub & 0xffff0000u);
          *(unsigned*)&P[wave][qf * 16 + l16][kf * 16 + quad * 4 + r] = pk;
        }
    #pragma unroll
    for (int qf = 0; qf < 2; qf++) {
      short8 pf = *(const short8*)&P[wave][qf * 16 + l16][quad * 8];
      acc[0][qf] = __builtin_amdgcn_mfma_f32_16x16x32_bf16(va, pf, acc[0][qf], 0, 0, 0);
      acc[1][qf] = __builtin_amdgcn_mfma_f32_16x16x32_bf16(vc, pf, acc[1][qf], 0, 0, 0);
    }
    ka = nka; kc = nkc; va = nva; vc = nvc;
  }
  #pragma unroll
  for (int qf = 0; qf < 2; qf++) {
    lsum[qf] += __shfl_xor(lsum[qf], 16);
    lsum[qf] += __shfl_xor(lsum[qf], 32);
  }
  #pragma unroll
  for (int df = 0; df < 2; df++)
    #pragma unroll
    for (int qf = 0; qf < 2; qf++) {
      int qg = q0 + qf * 16 + l16;
      if (qg < 900) {
        float inv = 1.f / lsum[qf];
        int d0 = df * 16 + quad * 4;
        short4v o4;
        o4.x = f2bf(acc[df][qf][0] * inv);
        o4.y = f2bf(acc[df][qf][1] * inv);
        o4.z = f2bf(acc[df][qf][2] * inv);
        o4.w = f2bf(acc[df][qf][3] * inv);
        *(short4v*)(att + (long)(qg * 8 + b) * 256 + h * 32 + d0) = o4;
      }
    }
}

// -------------------- residual + layernorm (optional bf16 / transposed bf16+pe out) ----
template<int BMODE>
__global__ __launch_bounds__(256) void resid_ln(
    const float* __restrict__ X, const float* __restrict__ R,
    const float* __restrict__ g, const float* __restrict__ be,
    float* __restrict__ out, short* __restrict__ obf,
    const float* __restrict__ qpe, short* __restrict__ obft) {
  int row = blockIdx.x;
  int d = threadIdx.x;
  long rrow;
  if (BMODE == 0) rrow = row;
  else { int b = row % B_BATCH; int n = row / B_BATCH; rrow = (long)b * NQ + n; }
  float x = X[(long)row * 256 + d] + R[rrow * 256 + d];
  float s1 = x, s2 = x * x;
  #pragma unroll
  for (int off = 32; off; off >>= 1) {
    s1 += __shfl_xor(s1, off);
    s2 += __shfl_xor(s2, off);
  }
  __shared__ float a1[4], a2[4];
  int w = d >> 6, lidx = d & 63;
  if (lidx == 0) { a1[w] = s1; a2[w] = s2; }
  __syncthreads();
  float S1 = a1[0] + a1[1] + a1[2] + a1[3];
  float S2 = a2[0] + a2[1] + a2[2] + a2[3];
  float mean = S1 * (1.f / 256.f);
  float var = S2 * (1.f / 256.f) - mean * mean;
  float y = (x - mean) * rsqrtf(var + 1e-5f) * g[d] + be[d];
  out[(long)row * 256 + d] = y;
  if (obf) obf[(long)row * 256 + d] = f2bf(y);
  if (obft) {   // row = n*B+b ; write bf16(y + qpe) at (b*NQ+n)
    int n = row >> 3, b = row & 7;
    obft[((long)b * NQ + n) * 256 + d] = f2bf(y + qpe[(long)row * 256 + d]);
  }
}

// -------------------- deformable-attention sampling (bf16 value, bf16 out) ------------
// offs/aw share a combined buffer with row stride 384.
// value is in (s, b, d) layout (matches input memory; no transpose in gemm_val).
__global__ __launch_bounds__(256) void deform_sample(
    const unsigned short* __restrict__ value, const float* __restrict__ offs,
    const float* __restrict__ aw, const float* __restrict__ qrp,
    short* __restrict__ samp) {
  int bq = blockIdx.x;  // b*NQ + q
  int b = bq / NQ, q = bq % NQ;
  int h = threadIdx.x >> 5, c = threadIdx.x & 31;
  __shared__ float Wl[8][16], Lx[8][16], Ly[8][16];
  if (c < 16) {
    float a = aw[(long)bq * 384 + h * 16 + c];
    float ox = offs[(long)bq * 384 + (h * 16 + c) * 2 + 0];
    float oy = offs[(long)bq * 384 + (h * 16 + c) * 2 + 1];
    const float* rp = qrp + ((long)q * B_BATCH + b) * 4;
    Lx[h][c] = rp[0] + ox * 0.25f * rp[2] * 0.5f;
    Ly[h][c] = rp[1] + oy * 0.25f * rp[3] * 0.5f;
    Wl[h][c] = a;
  }
  __syncthreads();
  if (threadIdx.x < 8) {
    int hh = threadIdx.x;
    float mx = -1e30f;
    for (int i = 0; i < 16; i++) mx = fmaxf(mx, Wl[hh][i]);
    float sm = 0.f;
    for (int i = 0; i < 16; i++) { float e = __expf(Wl[hh][i] - mx); Wl[hh][i] = e; sm += e; }
    float inv = 1.f / sm;
    for (int i = 0; i < 16; i++) Wl[hh][i] *= inv;
  }
  __syncthreads();
  const int lvlW[4] = {96, 48, 24, 12};
  const int lvlS[4] = {0, 9216, 11520, 12096};
  float acc = 0.f;
  // (s,b) layout: element (s_idx, b, h*32+c) at ((s_idx*8 + b)*256 + h*32+c)
  const unsigned short* vb = value + (long)b * 256 + h * 32 + c;
  #pragma unroll
  for (int l = 0; l < 4; l++) {
    int ww = lvlW[l], hh2 = lvlW[l], st = lvlS[l];
    #pragma unroll
    for (int p = 0; p < 4; p++) {
      int lp = l * 4 + p;
      float wgt = Wl[h][lp];
      float x = Lx[h][lp] * ww - 0.5f;
      float y = Ly[h][lp] * hh2 - 0.5f;
      float x0f = floorf(x), y0f = floorf(y);
      float lx = x - x0f, ly = y - y0f;
      int x0 = (int)x0f, y0 = (int)y0f;
      #pragma unroll
      for (int cy = 0; cy < 2; cy++) {
        #pragma unroll
        for (int cx = 0; cx < 2; cx++) {
          int xi = x0 + cx, yi = y0 + cy;
          float cw = (cx ? lx : 1.f - lx) * (cy ? ly : 1.f - ly);
          bool valid = (xi >= 0) && (xi < ww) && (yi >= 0) && (yi < hh2);
          int xc = min(max(xi, 0), ww - 1);
          int yc = min(max(yi, 0), hh2 - 1);
          float vv = bf2f(vb[(long)(st + yc * ww + xc) * 2048]);
          acc += (valid ? cw * wgt : 0.f) * vv;
        }
      }
    }
  }
  samp[(long)bq * 256 + h * 32 + c] = f2bf(acc);
}

// -------------------- host launch --------------------
extern "C" void kernel_launch(void* const* d_in, const int* in_sizes, int n_in,
                              void* d_out, int out_size, void* d_ws, size_t ws_size,
                              hipStream_t stream) {
  const float* queries = (const float*)d_in[0];
  const float* qpe     = (const float*)d_in[1];
  const float* qrp     = (const float*)d_in[2];
  const float* memory  = (const float*)d_in[3];
  const float* in_w    = (const float*)d_in[7];
  const float* in_b    = (const float*)d_in[8];
  const float* out_w   = (const float*)d_in[9];
  const float* out_b   = (const float*)d_in[10];
  const float* n1g = (const float*)d_in[11];
  const float* n1b = (const float*)d_in[12];
  const float* n2g = (const float*)d_in[13];
  const float* n2b = (const float*)d_in[14];
  const float* n3g = (const float*)d_in[15];
  const float* n3b = (const float*)d_in[16];
  const float* l1w = (const float*)d_in[17];
  const float* l1b = (const float*)d_in[18];
  const float* l2w = (const float*)d_in[19];
  const float* l2b = (const float*)d_in[20];
  const float* off_w = (const float*)d_in[21];
  const float* off_b = (const float*)d_in[22];
  const float* aw_w  = (const float*)d_in[23];
  const float* aw_b  = (const float*)d_in[24];
  const float* val_w = (const float*)d_in[25];
  const float* val_b = (const float*)d_in[26];
  const float* cout_w = (const float*)d_in[27];
  const float* cout_b = (const float*)d_in[28];

  float* ws = (float*)d_ws;
  const long E = (long)NROW * 256;        // 1,843,200
  float* slotA = ws + 0 * E;   // combined offs/aw [7200,384] (spans 2 slots)
  float* slotC = ws + 2 * E;   // sa -> ca -> ffn
  float* slotE = ws + 3 * E;   // q2
  float* slotF = ws + 4 * E;   // q3
  short* bfA = (short*)(ws + 5 * E);  // qk_bf -> samp_bf
  short* bfB = bfA + E;               // queries_bf -> qin_bf
  short* bfC = bfB + E;               // att_bf -> q3_bf
  short* wbf = bfC + E;               // weights bf16
  short* membt = wbf + 1540096;       // qk_h/vT -> hidden
  short* valbf = membt + 25067520;    // value bf16

  short* qk_h = membt;                          // [2][64][928][32]
  short* vT   = membt + 2L * 64 * KPAD * 32;    // [64][32][928]

  short* w_in   = wbf;                 // 196608 (Wq/Wk/Wv)
  short* w_out  = w_in + 196608;
  short* w_off  = w_out + 65536;       // [256,256]
  short* w_aw   = w_off + 65536;       // [128,256] (contiguous -> [384,256])
  short* w_val  = w_aw + 32768;
  short* w_cout = w_val + 65536;
  short* w_l1   = w_cout + 65536;
  short* w_l2   = w_l1 + 524288;
  float* bias_offaw = (float*)(valbf + 25067520);  // 384 floats

  dim3 blk(256);
  dim3 g7200(NROW);

  // 0. fused prep: weights -> bf16 + qk_bf/q_bf
  WConvArgs wa;
  wa.src[0] = in_w;  wa.dst[0] = w_in;
  wa.src[1] = out_w; wa.dst[1] = w_out;
  wa.src[2] = off_w; wa.dst[2] = w_off;
  wa.src[3] = aw_w;  wa.dst[3] = w_aw;
  wa.src[4] = val_w; wa.dst[4] = w_val;
  wa.src[5] = cout_w;wa.dst[5] = w_cout;
  wa.src[6] = l1w;   wa.dst[6] = w_l1;
  wa.src[7] = l2w;   wa.dst[7] = w_l2;
  int cs[8] = {196608, 65536, 65536, 32768, 65536, 65536, 524288, 524288};
  int acc0 = 0;
  for (int i = 0; i < 8; i++) { acc0 += cs[i]; wa.end[i] = acc0; }
  wa.total = acc0;
  int nbw = (acc0 + 255) / 256;
  prep_kernel<<<dim3(NB_ADD + nbw), blk, 0, stream>>>(wa, queries, qpe, bfA, bfB);
  hipMemcpyAsync(bias_offaw, off_b, 256 * sizeof(float), hipMemcpyDeviceToDevice, stream);
  hipMemcpyAsync(bias_offaw + 256, aw_b, 128 * sizeof(float), hipMemcpyDeviceToDevice, stream);

  // 1. in-proj: QK fused (N=512) -> head-split qk_h; V -> transposed vT
  gemm_bf16<false, 2, 128><<<dim3(4, 57), blk, 0, stream>>>(bfA, w_in, in_b, qk_h, NROW, 512, 256, 512);
  gemm_bf16<false, 3, 64><<<dim3(2, 113), blk, 0, stream>>>(bfB, w_in + 131072, in_b + 512, vT, NROW, 256, 256, 256);
  // 2. MFMA flash self-attention -> att_bf (bfC)
  attn_mfma<<<dim3(8, 64), blk, 0, stream>>>(qk_h, vT, bfC);
  // 3. out-proj -> sa (slotC)
  gemm_bf16<false, 0, 64><<<dim3(2, 113), blk, 0, stream>>>(bfC, w_out, out_b, slotC, NROW, 256, 256, 256);
  // 4. q2 = LN(queries + sa) [norm2] -> slotE; fused qin_bf -> bfB
  resid_ln<0><<<g7200, blk, 0, stream>>>(queries, slotC, n2g, n2b, slotE, nullptr, qpe, bfB);
  // 5. combined offsets+aw projection (N=384, LDC=384) -> slotA
  gemm_bf16<false, 0, 64><<<dim3(3, 113), blk, 0, stream>>>(bfB, w_off, bias_offaw, slotA, NROW, 384, 256, 384);
  // 6. value projection, (s,b) layout preserved (no transpose) -> valbf (v8)
  gemm_val<<<dim3(2, 1530), blk, 0, stream>>>(memory, w_val, val_b, valbf);
  // 7. deformable sampling ((s,b)-layout value) -> samp_bf (bfA)
  deform_sample<<<g7200, blk, 0, stream>>>((const unsigned short*)valbf, slotA, slotA + 256, qrp, bfA);
  // 8. cross-attn output proj -> ca (slotC)
  gemm_bf16<false, 0, 64><<<dim3(2, 113), blk, 0, stream>>>(bfA, w_cout, cout_b, slotC, NROW, 256, 256, 256);
  // 9. q3 = LN(q2 + ca^T) [norm1] -> slotF (+ bf16 copy in bfC)
  resid_ln<1><<<g7200, blk, 0, stream>>>(slotE, slotC, n1g, n1b, slotF, bfC, nullptr, nullptr);
  // 10. FFN lin1 + relu -> hidden bf16 (membt reuse)
  gemm_bf16<true, 1, 128><<<dim3(16, 57), blk, 0, stream>>>(bfC, w_l1, l1b, membt, NROW, DFF, 256, DFF);
  // 11. FFN lin2 -> ffn (slotC)
  gemm_bf16<false, 0, 64><<<dim3(2, 113), blk, 0, stream>>>(membt, w_l2, l2b, slotC, NROW, 256, 2048, 256);
  // 12. out = LN(q3 + ffn) [norm3]
  resid_ln<0><<<g7200, blk, 0, stream>>>(slotF, slotC, n3g, n3b, (float*)d_out, nullptr, nullptr, nullptr);
}